// Round 4
// baseline (4664.902 us; speedup 1.0000x reference)
//
#include <hip/hip_runtime.h>
#include <math.h>

#define BB 64
#define TT 512
#define FF 512
#define DIN 1024
#define HH 1024
#define G4 4096
#define DOUT 128

typedef _Float16 f16;
typedef _Float16 f16x4 __attribute__((ext_vector_type(4)));
typedef _Float16 f16x8 __attribute__((ext_vector_type(8)));
typedef float f32x4 __attribute__((ext_vector_type(4)));

// A-fragment-linear layout for a [64 x 1024] fp16 activation matrix:
//   element (m, k) -> ((k>>5)*4 + (m>>4))*512 + ((((k>>3)&3)<<4) | (m&15))*8 + (k&7)
__device__ __forceinline__ size_t afrag_off(int m, int k) {
    return (size_t)(((k >> 5) * 4 + (m >> 4)) * 512 + (((((k >> 3) & 3) << 4) | (m & 15)) * 8) + (k & 7));
}

// agent-scope write-through 16-B store (IF authoritative for cross-XCD readers)
__device__ __forceinline__ void store_b128_sc1(void* p, f32x4 v) {
    asm volatile("global_store_dwordx4 %0, %1, off sc1" :: "v"(p), "v"(v) : "memory");
}

// A-fragment load batch: 32 x 16B into a0v/a1v (kept as a macro so the
// compiler batches loads ahead of the MFMA loop -- do NOT refactor into a
// helper function; that sank loads into the MFMA loop in rounds 1-2).
#define LOADA()                                                            \
    _Pragma("unroll")                                                      \
    for (int ii = 0; ii < 16; ++ii) {                                      \
        a0v[ii] = *(const f16x8*)(Ap + (size_t)(ii * 4) * 512);            \
        a1v[ii] = *(const f16x8*)(Ap + (size_t)(ii * 4 + 1) * 512);        \
    }

// ---------------------------------------------------------------------------
// Pack cat(W,U) [2048 x 4096] fp32 -> fp16 B-fragment-linear, z-cols reordered
// as col' = j*4 + g. Per (cg, kstep) a contiguous 1KB fragment tile.
// ---------------------------------------------------------------------------
__global__ __launch_bounds__(64) void k_pack(
    const float* __restrict__ W, const float* __restrict__ U, f16* __restrict__ out)
{
    const int kstep = blockIdx.x, cg = blockIdx.y, l = threadIdx.x;
    const int n = l & 15, q = l >> 4;
    const int stdcol = (n & 3) * HH + cg * 4 + (n >> 2);
    f16x8 v;
#pragma unroll
    for (int e = 0; e < 8; ++e) {
        int k = kstep * 32 + q * 8 + e;
        float s = (k < DIN) ? W[(size_t)k * G4 + stdcol] : U[(size_t)(k - DIN) * G4 + stdcol];
        v[e] = (f16)s;
    }
    *(f16x8*)(out + ((size_t)(cg * 64 + kstep) * 64 + l) * 8) = v;
}

// ---------------------------------------------------------------------------
// Pack Wi [512 x 1024] fp32 -> fp16 B-frag (no gate reorder). Tile (nt, kstep).
// ---------------------------------------------------------------------------
__global__ __launch_bounds__(64) void k_pack_wi(
    const float* __restrict__ Wi, f16* __restrict__ out)
{
    const int kstep = blockIdx.x;   // 0..15
    const int nt    = blockIdx.y;   // 0..63
    const int l = threadIdx.x;
    const int n = nt * 16 + (l & 15), q = l >> 4;
    f16x8 v;
#pragma unroll
    for (int e = 0; e < 8; ++e)
        v[e] = (f16)Wi[(size_t)(kstep * 32 + q * 8 + e) * DIN + n];
    *(f16x8*)(out + ((size_t)(nt * 16 + kstep) * 64 + l) * 8) = v;
}

// ---------------------------------------------------------------------------
// MFMA input dense: XinF[t] = tanh(x[:,t,:] @ Wi + bi), f16 A-frag layout.
// One block per t; stage x[:,t,:] as f16 in LDS [64][520]; 4 waves x 4 N-groups.
// ---------------------------------------------------------------------------
__global__ __launch_bounds__(256) void k_dense_in2(
    const float* __restrict__ x, const f16* __restrict__ pWi,
    const float* __restrict__ bi, f16* __restrict__ XinF)
{
    extern __shared__ f16 xs[];   // 64 x 520 = 66560 B
    const int t = blockIdx.x;
    const int tid = threadIdx.x;

#pragma unroll
    for (int it = 0; it < 32; ++it) {
        int idx = tid + it * 256;          // 0..8191 float4s
        int r = idx >> 7, c4 = idx & 127;
        float4 v = *(const float4*)(x + ((size_t)r * TT + t) * FF + c4 * 4);
        f16x4 hv = {(f16)v.x, (f16)v.y, (f16)v.z, (f16)v.w};
        *(f16x4*)(xs + (size_t)r * 520 + c4 * 4) = hv;
    }
    __syncthreads();

    const int w = tid >> 6, lane = tid & 63;
    const int col = lane & 15, rq = lane >> 4;
#pragma unroll 1
    for (int g = 0; g < 4; ++g) {
        f32x4 acc[4][4];
#pragma unroll
        for (int a = 0; a < 4; ++a)
#pragma unroll
            for (int b = 0; b < 4; ++b) acc[a][b] = (f32x4){0.f, 0.f, 0.f, 0.f};
#pragma unroll 2
        for (int ks2 = 0; ks2 < 16; ++ks2) {
            f16x8 bf[4];
#pragma unroll
            for (int nn = 0; nn < 4; ++nn)
                bf[nn] = *(const f16x8*)(pWi + ((size_t)((w * 16 + g * 4 + nn) * 16 + ks2) * 64 + lane) * 8);
#pragma unroll
            for (int mt = 0; mt < 4; ++mt) {
                f16x8 af = *(const f16x8*)(xs + (size_t)(mt * 16 + col) * 520 + ks2 * 32 + rq * 8);
#pragma unroll
                for (int nn = 0; nn < 4; ++nn)
                    acc[mt][nn] = __builtin_amdgcn_mfma_f32_16x16x32_f16(af, bf[nn], acc[mt][nn], 0, 0, 0);
            }
        }
#pragma unroll
        for (int nn = 0; nn < 4; ++nn) {
            const int j = (w * 16 + g * 4 + nn) * 16 + col;
            const float bb = bi[j];
#pragma unroll
            for (int mt = 0; mt < 4; ++mt)
#pragma unroll
                for (int r = 0; r < 4; ++r)
                    XinF[(size_t)t * (BB * DIN) + afrag_off(mt * 16 + rq * 4 + r, j)]
                        = (f16)tanhf(acc[mt][nn][r] + bb);
        }
    }
}

// ---------------------------------------------------------------------------
// Persistent kernel, 256 blocks x 512 threads (1 block/CU).
// lay = bid&1, cgb = bid>>1 (8 hidden units). Weights in LDS once.
// Sync (round 4): per-phase single counters, no aggregator. Producer tid0
// does one agent-scope atomicAdd to cnt[lay] word for phase p (64-B strided
// so adjacent phases don't share a line). Consumer tid0 polls
// cnt[..][p-1] >= 128. L0 gates only on cnt0 (not gated on L1 at all, so it
// runs ahead); L1 gates on cnt0[p-1] (usually pre-satisfied), prefetches its
// h0-half A-frags, then gates on cnt1[p-1].
// h: write-once history, sc1 write-through 16-B stores. Cell state c in regs.
// Epilogue: conflict-free buf[4 kq][64 rows][stride 20] f32, repack folded
// into n==1 reduce. GEMM source shape byte-identical to the round-0 baseline.
// ---------------------------------------------------------------------------
__global__ __launch_bounds__(512, 2) void k_persist(
    const f16* __restrict__ XinF,
    f16* __restrict__ h0b_, f16* __restrict__ h1b_,
    const f16* __restrict__ pW0, const f16* __restrict__ pW1,
    const float* __restrict__ b0, const float* __restrict__ b1,
    unsigned* __restrict__ flags)
{
    extern __shared__ char smem[];
    f16*   bsh  = (f16*)smem;                    // 131072 B weight fragments
    float* buf  = (float*)(smem + 131072);       // 4 x 64 x 20 f32 = 20480 B
    f16*   hrow = (f16*)(smem + 131072 + 20480); // 64 x 8 f16 = 1024 B

    const int lay = blockIdx.x & 1;
    const int cgb = blockIdx.x >> 1;
    const int tid = threadIdx.x;
    const int wv = tid >> 6, lane = tid & 63;
    const int kq = wv >> 1, mh = wv & 1;

    // per-phase arrival counters, 16 words (64 B) apart; 513 phases per layer
    unsigned* cnt0 = flags;                      // L0: [513 * 16]
    unsigned* cnt1 = flags + 513 * 16;           // L1: [513 * 16]
    unsigned* cntOwn = lay ? cnt1 : cnt0;

    // ---- stage this block's weight slice into LDS (once) ----
    {
        const f16x8* s8 = (const f16x8*)((lay ? pW1 : pW0) + (size_t)(cgb * 2) * 64 * 512);
        f16x8* d8 = (f16x8*)bsh;
#pragma unroll
        for (int it = 0; it < 16; ++it) d8[tid + it * 512] = s8[tid + it * 512];
    }

    // ---- epilogue-role constants ----
    const float* bias = lay ? b1 : b0;
    const int erow = tid & 63, ejl = (tid >> 6) & 3;
    float bz[2][4];
    float creg[2] = {0.f, 0.f};
    if (tid < 256) {
#pragma unroll
        for (int n = 0; n < 2; ++n) {
            const int jg = (cgb * 2 + n) * 4 + ejl;
#pragma unroll
            for (int g = 0; g < 4; ++g) bz[n][g] = bias[g * HH + jg];
        }
    }

    const size_t HBUF = (size_t)BB * DIN;
    const f16* bq = bsh + (size_t)(kq * 16 * 64 + lane) * 8;
    const int colw = lane & 15, rg = lane >> 4;
    __syncthreads();

    for (int p = 0; p <= TT; ++p) {
        if (lay == 0 && p == TT) break;          // L0 finished at p=511
        const bool active = lay ? (p >= 1) : true;

        if (active) {
            const f16* Abase;
            if (lay == 0) Abase = (kq < 2) ? (XinF + (size_t)p * HBUF) : (h0b_ + (size_t)p * HBUF);
            else          Abase = (kq < 2) ? (h0b_ + (size_t)p * HBUF) : (h1b_ + (size_t)(p - 1) * HBUF);
            f16* hw = lay ? (h1b_ + (size_t)p * HBUF) : (h0b_ + (size_t)(p + 1) * HBUF);
            const f16* Ap = Abase + (size_t)(((kq & 1) * 64 + mh * 2) * 512) + (size_t)lane * 8;

            f16x8 a0v[16], a1v[16];
            const bool preW = (kq < 2);          // first-half waves (Xin / h0)

            // L0's Xin half is static: load before any gate
            if (lay == 0 && preW) { LOADA(); }

            // ---- gate 1: h0-producer layer progress (cnt0) ----
            if (lay == 0) {
                if (p > 0) {
                    if (tid == 0)
                        while (__hip_atomic_load(&cnt0[(size_t)(p - 1) * 16],
                                                 __ATOMIC_RELAXED, __HIP_MEMORY_SCOPE_AGENT) < 128u)
                            __builtin_amdgcn_s_sleep(1);
                    __syncthreads();
                }
            } else {
                if (tid == 0)
                    while (__hip_atomic_load(&cnt0[(size_t)(p - 1) * 16],
                                             __ATOMIC_RELAXED, __HIP_MEMORY_SCOPE_AGENT) < 128u)
                        __builtin_amdgcn_s_sleep(1);
                __syncthreads();

                // h0[p] now certified: prefetch L1's h0 half before gate 2
                if (preW) { LOADA(); }

                // ---- gate 2: own-layer progress (cnt1) ----
                if (tid == 0)
                    while (__hip_atomic_load(&cnt1[(size_t)(p - 1) * 16],
                                             __ATOMIC_RELAXED, __HIP_MEMORY_SCOPE_AGENT) < 128u)
                        __builtin_amdgcn_s_sleep(1);
                __syncthreads();
            }

            // second-half waves (h0 for L0, h1 for L1) load post-gate
            if (!preW) { LOADA(); }

            f32x4 acc00 = {0.f,0.f,0.f,0.f}, acc01 = {0.f,0.f,0.f,0.f};
            f32x4 acc10 = {0.f,0.f,0.f,0.f}, acc11 = {0.f,0.f,0.f,0.f};
#pragma unroll
            for (int ii = 0; ii < 16; ++ii) {
                f16x8 bb0 = *(const f16x8*)(bq + (size_t)ii * 512);
                f16x8 bb1 = *(const f16x8*)(bq + 32768 + (size_t)ii * 512);
                acc00 = __builtin_amdgcn_mfma_f32_16x16x32_f16(a0v[ii], bb0, acc00, 0, 0, 0);
                acc01 = __builtin_amdgcn_mfma_f32_16x16x32_f16(a0v[ii], bb1, acc01, 0, 0, 0);
                acc10 = __builtin_amdgcn_mfma_f32_16x16x32_f16(a1v[ii], bb0, acc10, 0, 0, 0);
                acc11 = __builtin_amdgcn_mfma_f32_16x16x32_f16(a1v[ii], bb1, acc11, 0, 0, 0);
            }

            // ---- epilogue: two n-rounds over conflict-free buf[kq][row][20] ----
            f16 hvv[2];
#pragma unroll 1
            for (int n = 0; n < 2; ++n) {
                float* t0 = buf + (size_t)kq * 1280 + (size_t)(mh * 32 + rg * 4) * 20 + colw;
#pragma unroll
                for (int r = 0; r < 4; ++r) {
                    t0[r * 20]           = n ? acc01[r] : acc00[r];
                    t0[16 * 20 + r * 20] = n ? acc11[r] : acc10[r];
                }
                __syncthreads();
                if (tid < 256) {
                    f32x4 z = {0.f, 0.f, 0.f, 0.f};
#pragma unroll
                    for (int k2 = 0; k2 < 4; ++k2)
                        z += *(const f32x4*)(buf + (size_t)k2 * 1280 + (size_t)erow * 20 + ejl * 4);
                    const float z0 = z[0] + bz[n][0];
                    const float z1 = z[1] + bz[n][1];
                    const float z2 = z[2] + bz[n][2];
                    const float z3 = z[3] + bz[n][3];
                    const float ig = 1.f / (1.f + expf(-z0));
                    const float fg = 1.f / (1.f + expf(-z1));
                    const float cc = tanhf(z2);
                    const float og = 1.f / (1.f + expf(-z3));
                    const float cn = fg * creg[n] + ig * cc;
                    creg[n] = cn;
                    hvv[n] = (f16)(og * tanhf(cn));
                    if (n == 1) {   // fold repack into the last reduce round
                        hrow[erow * 8 + ejl]     = hvv[0];
                        hrow[erow * 8 + 4 + ejl] = hvv[1];
                    }
                }
                __syncthreads();
            }

            // ---- one 16-B sc1 store per row (wave0 only) ----
            if (tid < 64) {
                f32x4 v = *(f32x4*)(hrow + tid * 8);
                store_b128_sc1(hw + afrag_off(tid, cgb * 8), v);
            }
        }

        // ---- arrival: wave0 drains its h stores, tid0 bumps the phase counter ----
        asm volatile("s_waitcnt vmcnt(0)" ::: "memory");
        if (tid == 0)
            __hip_atomic_fetch_add(&cntOwn[(size_t)p * 16], 1u,
                                   __ATOMIC_RELAXED, __HIP_MEMORY_SCOPE_AGENT);
    }
}

// ---------------------------------------------------------------------------
// Kernel 3: out[b][o] = tanh(h1[b,:] @ Wo[:,o] + bo[o]); h1 in fp16 A-frag.
// ---------------------------------------------------------------------------
__global__ __launch_bounds__(128) void k_out(
    const f16* __restrict__ h1f, const float* __restrict__ Wo,
    const float* __restrict__ bo, float* __restrict__ out)
{
    __shared__ float hs[HH];
    const int b = blockIdx.x;
    for (int i = threadIdx.x; i < HH; i += 128) hs[i] = (float)h1f[afrag_off(b, i)];
    __syncthreads();
    const int o = threadIdx.x;
    float acc = 0.f;
    for (int k = 0; k < HH; ++k) acc += hs[k] * Wo[k * DOUT + o];
    out[b * DOUT + o] = tanhf(acc + bo[o]);
}

// ---------------------------------------------------------------------------
extern "C" void kernel_launch(void* const* d_in, const int* in_sizes, int n_in,
                              void* d_out, int out_size, void* d_ws, size_t ws_size,
                              hipStream_t stream)
{
    const float* x  = (const float*)d_in[0];
    const float* Wi = (const float*)d_in[1];
    const float* bi = (const float*)d_in[2];
    const float* W0 = (const float*)d_in[3];
    const float* U0 = (const float*)d_in[4];
    const float* b0 = (const float*)d_in[5];
    const float* W1 = (const float*)d_in[6];
    const float* U1 = (const float*)d_in[7];
    const float* b1 = (const float*)d_in[8];
    const float* Wo = (const float*)d_in[9];
    const float* bo = (const float*)d_in[10];
    float* out = (float*)d_out;

    f16* ws16 = (f16*)d_ws;
    const size_t HBUF = (size_t)BB * DIN;          // 65536 f16
    f16* XinF = ws16;                              // 512 bufs
    f16* pW0  = XinF + (size_t)TT * HBUF;
    f16* pW1  = pW0 + (size_t)2048 * G4;
    f16* pWi  = pW1 + (size_t)2048 * G4;           // 512*1024
    f16* h0   = pWi + (size_t)FF * DIN;            // 513 bufs (write-once hist)
    f16* h1   = h0 + (size_t)513 * HBUF;           // 513 bufs
    unsigned* flags = (unsigned*)(h1 + (size_t)513 * HBUF);

    // zero initial h0[-1], h1[-1] and the counter region (2 x 513 x 16 words)
    hipMemsetAsync(h0, 0, HBUF * sizeof(f16), stream);
    hipMemsetAsync(h1, 0, HBUF * sizeof(f16), stream);
    hipMemsetAsync(flags, 0, 131072, stream);

    k_pack<<<dim3(64, 256), 64, 0, stream>>>(W0, U0, pW0);
    k_pack<<<dim3(64, 256), 64, 0, stream>>>(W1, U1, pW1);
    k_pack_wi<<<dim3(16, 64), 64, 0, stream>>>(Wi, pWi);

    hipFuncSetAttribute((const void*)k_dense_in2,
                        hipFuncAttributeMaxDynamicSharedMemorySize, 66560);
    k_dense_in2<<<TT, 256, 66560, stream>>>(x, pWi, bi, XinF);

    {
        const int smem_bytes = 131072 + 20480 + 1024;   // 152576 B
        hipFuncSetAttribute((const void*)k_persist,
                            hipFuncAttributeMaxDynamicSharedMemorySize, smem_bytes);
        const f16* XinF_c = XinF;
        const f16* pW0_c = pW0;
        const f16* pW1_c = pW1;
        f16 *h0_v = h0, *h1_v = h1;
        const float *b0_v = b0, *b1_v = b1;
        unsigned* flags_v = flags;
        void* kargs[] = {
            (void*)&XinF_c,
            (void*)&h0_v, (void*)&h1_v,
            (void*)&pW0_c, (void*)&pW1_c,
            (void*)&b0_v, (void*)&b1_v,
            (void*)&flags_v
        };
        hipLaunchCooperativeKernel((void*)k_persist, dim3(256), dim3(512),
                                   kargs, smem_bytes, stream);
    }

    // h1[511] lives at h1 + 512*HBUF
    k_out<<<BB, 128, 0, stream>>>(h1 + (size_t)512 * HBUF, Wo, bo, out);
}

// Round 5
// 4398.045 us; speedup vs baseline: 1.0607x; 1.0607x over previous
//
#include <hip/hip_runtime.h>
#include <math.h>

#define BB 64
#define TT 512
#define FF 512
#define DIN 1024
#define HH 1024
#define G4 4096
#define DOUT 128

typedef _Float16 f16;
typedef _Float16 f16x4 __attribute__((ext_vector_type(4)));
typedef _Float16 f16x8 __attribute__((ext_vector_type(8)));
typedef float f32x4 __attribute__((ext_vector_type(4)));

// A-fragment-linear layout for a [64 x 1024] fp16 activation matrix:
//   element (m, k) -> ((k>>5)*4 + (m>>4))*512 + ((((k>>3)&3)<<4) | (m&15))*8 + (k&7)
__device__ __forceinline__ size_t afrag_off(int m, int k) {
    return (size_t)(((k >> 5) * 4 + (m >> 4)) * 512 + (((((k >> 3) & 3) << 4) | (m & 15)) * 8) + (k & 7));
}

// agent-scope write-through 16-B store (IF authoritative for cross-XCD readers)
__device__ __forceinline__ void store_b128_sc1(void* p, f32x4 v) {
    asm volatile("global_store_dwordx4 %0, %1, off sc1" :: "v"(p), "v"(v) : "memory");
}

// wave-uniform poll of one go word (all lanes load same address = 1 req/wave)
__device__ __forceinline__ void wave_poll(const unsigned* w, unsigned tgt) {
    while (__hip_atomic_load(w, __ATOMIC_RELAXED, __HIP_MEMORY_SCOPE_AGENT) < tgt)
        __builtin_amdgcn_s_sleep(2);
}

// One wave's K-half GEMM: 32 batched A-loads then 64 MFMAs, B from LDS.
// Kept as a textual macro (NOT a helper function): rounds 1-2 showed a helper
// makes the compiler sink loads into the MFMA loop (VGPR 100/44, serial L2
// latency per iteration). This shape reproduces round 0's proven codegen.
#define GEMM_BODY()                                                            \
    {                                                                          \
        f16x8 a0v[16], a1v[16];                                                \
        _Pragma("unroll")                                                      \
        for (int ii = 0; ii < 16; ++ii) {                                      \
            a0v[ii] = *(const f16x8*)(Ap + (size_t)(ii * 4) * 512);            \
            a1v[ii] = *(const f16x8*)(Ap + (size_t)(ii * 4 + 1) * 512);        \
        }                                                                      \
        _Pragma("unroll")                                                      \
        for (int ii = 0; ii < 16; ++ii) {                                      \
            f16x8 bb0 = *(const f16x8*)(bq + (size_t)ii * 512);                \
            f16x8 bb1 = *(const f16x8*)(bq + 32768 + (size_t)ii * 512);        \
            acc00 = __builtin_amdgcn_mfma_f32_16x16x32_f16(a0v[ii], bb0, acc00, 0, 0, 0); \
            acc01 = __builtin_amdgcn_mfma_f32_16x16x32_f16(a0v[ii], bb1, acc01, 0, 0, 0); \
            acc10 = __builtin_amdgcn_mfma_f32_16x16x32_f16(a1v[ii], bb0, acc10, 0, 0, 0); \
            acc11 = __builtin_amdgcn_mfma_f32_16x16x32_f16(a1v[ii], bb1, acc11, 0, 0, 0); \
        }                                                                      \
    }

// ---------------------------------------------------------------------------
// Pack cat(W,U) [2048 x 4096] fp32 -> fp16 B-fragment-linear, z-cols reordered
// as col' = j*4 + g. Per (cg, kstep) a contiguous 1KB fragment tile.
// ---------------------------------------------------------------------------
__global__ __launch_bounds__(64) void k_pack(
    const float* __restrict__ W, const float* __restrict__ U, f16* __restrict__ out)
{
    const int kstep = blockIdx.x, cg = blockIdx.y, l = threadIdx.x;
    const int n = l & 15, q = l >> 4;
    const int stdcol = (n & 3) * HH + cg * 4 + (n >> 2);
    f16x8 v;
#pragma unroll
    for (int e = 0; e < 8; ++e) {
        int k = kstep * 32 + q * 8 + e;
        float s = (k < DIN) ? W[(size_t)k * G4 + stdcol] : U[(size_t)(k - DIN) * G4 + stdcol];
        v[e] = (f16)s;
    }
    *(f16x8*)(out + ((size_t)(cg * 64 + kstep) * 64 + l) * 8) = v;
}

// ---------------------------------------------------------------------------
// Pack Wi [512 x 1024] fp32 -> fp16 B-frag (no gate reorder). Tile (nt, kstep).
// ---------------------------------------------------------------------------
__global__ __launch_bounds__(64) void k_pack_wi(
    const float* __restrict__ Wi, f16* __restrict__ out)
{
    const int kstep = blockIdx.x;   // 0..15
    const int nt    = blockIdx.y;   // 0..63
    const int l = threadIdx.x;
    const int n = nt * 16 + (l & 15), q = l >> 4;
    f16x8 v;
#pragma unroll
    for (int e = 0; e < 8; ++e)
        v[e] = (f16)Wi[(size_t)(kstep * 32 + q * 8 + e) * DIN + n];
    *(f16x8*)(out + ((size_t)(nt * 16 + kstep) * 64 + l) * 8) = v;
}

// ---------------------------------------------------------------------------
// MFMA input dense: XinF[t] = tanh(x[:,t,:] @ Wi + bi), f16 A-frag layout.
// One block per t; stage x[:,t,:] as f16 in LDS [64][520]; 4 waves x 4 N-groups.
// ---------------------------------------------------------------------------
__global__ __launch_bounds__(256) void k_dense_in2(
    const float* __restrict__ x, const f16* __restrict__ pWi,
    const float* __restrict__ bi, f16* __restrict__ XinF)
{
    extern __shared__ f16 xs[];   // 64 x 520 = 66560 B
    const int t = blockIdx.x;
    const int tid = threadIdx.x;

#pragma unroll
    for (int it = 0; it < 32; ++it) {
        int idx = tid + it * 256;          // 0..8191 float4s
        int r = idx >> 7, c4 = idx & 127;
        float4 v = *(const float4*)(x + ((size_t)r * TT + t) * FF + c4 * 4);
        f16x4 hv = {(f16)v.x, (f16)v.y, (f16)v.z, (f16)v.w};
        *(f16x4*)(xs + (size_t)r * 520 + c4 * 4) = hv;
    }
    __syncthreads();

    const int w = tid >> 6, lane = tid & 63;
    const int col = lane & 15, rq = lane >> 4;
#pragma unroll 1
    for (int g = 0; g < 4; ++g) {
        f32x4 acc[4][4];
#pragma unroll
        for (int a = 0; a < 4; ++a)
#pragma unroll
            for (int b = 0; b < 4; ++b) acc[a][b] = (f32x4){0.f, 0.f, 0.f, 0.f};
#pragma unroll 2
        for (int ks2 = 0; ks2 < 16; ++ks2) {
            f16x8 bf[4];
#pragma unroll
            for (int nn = 0; nn < 4; ++nn)
                bf[nn] = *(const f16x8*)(pWi + ((size_t)((w * 16 + g * 4 + nn) * 16 + ks2) * 64 + lane) * 8);
#pragma unroll
            for (int mt = 0; mt < 4; ++mt) {
                f16x8 af = *(const f16x8*)(xs + (size_t)(mt * 16 + col) * 520 + ks2 * 32 + rq * 8);
#pragma unroll
                for (int nn = 0; nn < 4; ++nn)
                    acc[mt][nn] = __builtin_amdgcn_mfma_f32_16x16x32_f16(af, bf[nn], acc[mt][nn], 0, 0, 0);
            }
        }
#pragma unroll
        for (int nn = 0; nn < 4; ++nn) {
            const int j = (w * 16 + g * 4 + nn) * 16 + col;
            const float bb = bi[j];
#pragma unroll
            for (int mt = 0; mt < 4; ++mt)
#pragma unroll
                for (int r = 0; r < 4; ++r)
                    XinF[(size_t)t * (BB * DIN) + afrag_off(mt * 16 + rq * 4 + r, j)]
                        = (f16)tanhf(acc[mt][nn][r] + bb);
        }
    }
}

// ---------------------------------------------------------------------------
// Persistent kernel, 256 blocks x 512 threads (1 block/CU).
// lay = bid&1, cgb = bid>>1 (8 hidden units). Weights in LDS once.
// Sync (round 5):
//  - arrivals: per-phase counter word (64-B strided, writers-only line);
//    producer tid0 fetch_adds after sc1 h-store + vmcnt(0) drain; whoever
//    sees old==127 publishes go = p+1 to 8 per-line copies (no aggregator).
//  - gates: per-WAVE polling of go copy (cgb&7), no gate barriers. Each wave
//    gates only on its own data dependency:
//      L0 Xin-half: none.   L0 h0-half: go0 >= p (p>0).
//      L1 h0-half: go0 >= p (pre-satisfied; L0 free-runs ahead).
//      L1 h1-half: go1 >= p.
//    The epilogue barriers re-converge the block each phase; the static half's
//    GEMM runs entirely under the recurrent half's wait, with only 16 acc
//    VGPRs live across any poll.
// h: write-once history, sc1 write-through 16-B stores. Cell state c in regs.
// Epilogue: conflict-free buf[4 kq][64 rows][stride 20] f32, repack folded
// into n==1 reduce (validated rounds 1-3). GEMM codegen shape = round 0.
// ---------------------------------------------------------------------------
__global__ __launch_bounds__(512, 2) void k_persist(
    const f16* __restrict__ XinF,
    f16* __restrict__ h0b_, f16* __restrict__ h1b_,
    const f16* __restrict__ pW0, const f16* __restrict__ pW1,
    const float* __restrict__ b0, const float* __restrict__ b1,
    unsigned* __restrict__ flags)
{
    extern __shared__ char smem[];
    f16*   bsh  = (f16*)smem;                    // 131072 B weight fragments
    float* buf  = (float*)(smem + 131072);       // 4 x 64 x 20 f32 = 20480 B
    f16*   hrow = (f16*)(smem + 131072 + 20480); // 64 x 8 f16 = 1024 B

    const int lay = blockIdx.x & 1;
    const int cgb = blockIdx.x >> 1;
    const int tid = threadIdx.x;
    const int wv = tid >> 6, lane = tid & 63;
    const int kq = wv >> 1, mh = wv & 1;

    // flag layout (words): [2048..2303] go0 x8 copies (stride 32)
    //                      [2560..2815] go1 x8 copies (stride 32)
    //                      [4096..]     cnt0 per-phase (stride 16)
    //                      [4096+513*16..] cnt1 per-phase (stride 16)
    unsigned* goCpy0 = flags + 2048;
    unsigned* goCpy1 = flags + 2560;
    unsigned* cnt0   = flags + 4096;
    unsigned* cnt1   = flags + 4096 + 513 * 16;
    unsigned* cntOwn = lay ? cnt1 : cnt0;
    unsigned* goOwn  = lay ? goCpy1 : goCpy0;
    const unsigned* myGo0 = goCpy0 + (size_t)(cgb & 7) * 32;
    const unsigned* myGo1 = goCpy1 + (size_t)(cgb & 7) * 32;

    // ---- stage this block's weight slice into LDS (once) ----
    {
        const f16x8* s8 = (const f16x8*)((lay ? pW1 : pW0) + (size_t)(cgb * 2) * 64 * 512);
        f16x8* d8 = (f16x8*)bsh;
#pragma unroll
        for (int it = 0; it < 16; ++it) d8[tid + it * 512] = s8[tid + it * 512];
    }

    // ---- epilogue-role constants ----
    const float* bias = lay ? b1 : b0;
    const int erow = tid & 63, ejl = (tid >> 6) & 3;
    float bz[2][4];
    float creg[2] = {0.f, 0.f};
    if (tid < 256) {
#pragma unroll
        for (int n = 0; n < 2; ++n) {
            const int jg = (cgb * 2 + n) * 4 + ejl;
#pragma unroll
            for (int g = 0; g < 4; ++g) bz[n][g] = bias[g * HH + jg];
        }
    }

    const size_t HBUF = (size_t)BB * DIN;
    const f16* bq = bsh + (size_t)(kq * 16 * 64 + lane) * 8;
    const int colw = lane & 15, rg = lane >> 4;
    __syncthreads();

    for (int p = 0; p <= TT; ++p) {
        if (lay == 0 && p == TT) break;          // L0 finished at p=511
        const bool active = lay ? (p >= 1) : true;

        if (active) {
            const f16* Abase;
            if (lay == 0) Abase = (kq < 2) ? (XinF + (size_t)p * HBUF) : (h0b_ + (size_t)p * HBUF);
            else          Abase = (kq < 2) ? (h0b_ + (size_t)p * HBUF) : (h1b_ + (size_t)(p - 1) * HBUF);
            f16* hw = lay ? (h1b_ + (size_t)p * HBUF) : (h0b_ + (size_t)(p + 1) * HBUF);
            const f16* Ap = Abase + (size_t)(((kq & 1) * 64 + mh * 2) * 512) + (size_t)lane * 8;

            f32x4 acc00 = {0.f,0.f,0.f,0.f}, acc01 = {0.f,0.f,0.f,0.f};
            f32x4 acc10 = {0.f,0.f,0.f,0.f}, acc11 = {0.f,0.f,0.f,0.f};

            // ---- per-wave gate + GEMM (4 textual copies of the round-0 body) ----
            if (lay == 0) {
                if (kq < 2) {
                    // static Xin half: no gate, runs under the other half's wait
                    GEMM_BODY();
                } else {
                    if (p > 0) wave_poll(myGo0, (unsigned)p);
                    GEMM_BODY();
                }
            } else {
                if (kq < 2) {
                    wave_poll(myGo0, (unsigned)p);   // h0[p] ready (usually pre-satisfied)
                    GEMM_BODY();
                } else {
                    wave_poll(myGo1, (unsigned)p);   // h1[p-1] ready
                    GEMM_BODY();
                }
            }

            // ---- epilogue: two n-rounds over conflict-free buf[kq][row][20] ----
            f16 hvv[2];
#pragma unroll 1
            for (int n = 0; n < 2; ++n) {
                float* t0 = buf + (size_t)kq * 1280 + (size_t)(mh * 32 + rg * 4) * 20 + colw;
#pragma unroll
                for (int r = 0; r < 4; ++r) {
                    t0[r * 20]           = n ? acc01[r] : acc00[r];
                    t0[16 * 20 + r * 20] = n ? acc11[r] : acc10[r];
                }
                __syncthreads();
                if (tid < 256) {
                    f32x4 z = {0.f, 0.f, 0.f, 0.f};
#pragma unroll
                    for (int k2 = 0; k2 < 4; ++k2)
                        z += *(const f32x4*)(buf + (size_t)k2 * 1280 + (size_t)erow * 20 + ejl * 4);
                    const float z0 = z[0] + bz[n][0];
                    const float z1 = z[1] + bz[n][1];
                    const float z2 = z[2] + bz[n][2];
                    const float z3 = z[3] + bz[n][3];
                    const float ig = 1.f / (1.f + expf(-z0));
                    const float fg = 1.f / (1.f + expf(-z1));
                    const float cc = tanhf(z2);
                    const float og = 1.f / (1.f + expf(-z3));
                    const float cn = fg * creg[n] + ig * cc;
                    creg[n] = cn;
                    hvv[n] = (f16)(og * tanhf(cn));
                    if (n == 1) {   // fold repack into the last reduce round
                        hrow[erow * 8 + ejl]     = hvv[0];
                        hrow[erow * 8 + 4 + ejl] = hvv[1];
                    }
                }
                __syncthreads();
            }

            // ---- one 16-B sc1 store per row (wave0 only) ----
            if (tid < 64) {
                f32x4 v = *(f32x4*)(hrow + tid * 8);
                store_b128_sc1(hw + afrag_off(tid, cgb * 8), v);
            }
        }

        // ---- arrival: wave0 drains h stores; last arriver publishes go ----
        asm volatile("s_waitcnt vmcnt(0)" ::: "memory");
        if (tid == 0) {
            unsigned old = __hip_atomic_fetch_add(&cntOwn[(size_t)p * 16], 1u,
                                                  __ATOMIC_RELAXED, __HIP_MEMORY_SCOPE_AGENT);
            if (old == 127u) {
#pragma unroll
                for (int i = 0; i < 8; ++i)
                    __hip_atomic_store(goOwn + (size_t)i * 32, (unsigned)(p + 1),
                                       __ATOMIC_RELAXED, __HIP_MEMORY_SCOPE_AGENT);
            }
        }
    }
}

// ---------------------------------------------------------------------------
// Kernel 3: out[b][o] = tanh(h1[b,:] @ Wo[:,o] + bo[o]); h1 in fp16 A-frag.
// ---------------------------------------------------------------------------
__global__ __launch_bounds__(128) void k_out(
    const f16* __restrict__ h1f, const float* __restrict__ Wo,
    const float* __restrict__ bo, float* __restrict__ out)
{
    __shared__ float hs[HH];
    const int b = blockIdx.x;
    for (int i = threadIdx.x; i < HH; i += 128) hs[i] = (float)h1f[afrag_off(b, i)];
    __syncthreads();
    const int o = threadIdx.x;
    float acc = 0.f;
    for (int k = 0; k < HH; ++k) acc += hs[k] * Wo[k * DOUT + o];
    out[b * DOUT + o] = tanhf(acc + bo[o]);
}

// ---------------------------------------------------------------------------
extern "C" void kernel_launch(void* const* d_in, const int* in_sizes, int n_in,
                              void* d_out, int out_size, void* d_ws, size_t ws_size,
                              hipStream_t stream)
{
    const float* x  = (const float*)d_in[0];
    const float* Wi = (const float*)d_in[1];
    const float* bi = (const float*)d_in[2];
    const float* W0 = (const float*)d_in[3];
    const float* U0 = (const float*)d_in[4];
    const float* b0 = (const float*)d_in[5];
    const float* W1 = (const float*)d_in[6];
    const float* U1 = (const float*)d_in[7];
    const float* b1 = (const float*)d_in[8];
    const float* Wo = (const float*)d_in[9];
    const float* bo = (const float*)d_in[10];
    float* out = (float*)d_out;

    f16* ws16 = (f16*)d_ws;
    const size_t HBUF = (size_t)BB * DIN;          // 65536 f16
    f16* XinF = ws16;                              // 512 bufs
    f16* pW0  = XinF + (size_t)TT * HBUF;
    f16* pW1  = pW0 + (size_t)2048 * G4;
    f16* pWi  = pW1 + (size_t)2048 * G4;           // 512*1024
    f16* h0   = pWi + (size_t)FF * DIN;            // 513 bufs (write-once hist)
    f16* h1   = h0 + (size_t)513 * HBUF;           // 513 bufs
    unsigned* flags = (unsigned*)(h1 + (size_t)513 * HBUF);

    // zero initial h0[-1], h1[-1] and the go/counter region (82 KB used)
    hipMemsetAsync(h0, 0, HBUF * sizeof(f16), stream);
    hipMemsetAsync(h1, 0, HBUF * sizeof(f16), stream);
    hipMemsetAsync(flags, 0, 131072, stream);

    k_pack<<<dim3(64, 256), 64, 0, stream>>>(W0, U0, pW0);
    k_pack<<<dim3(64, 256), 64, 0, stream>>>(W1, U1, pW1);
    k_pack_wi<<<dim3(16, 64), 64, 0, stream>>>(Wi, pWi);

    hipFuncSetAttribute((const void*)k_dense_in2,
                        hipFuncAttributeMaxDynamicSharedMemorySize, 66560);
    k_dense_in2<<<TT, 256, 66560, stream>>>(x, pWi, bi, XinF);

    {
        const int smem_bytes = 131072 + 20480 + 1024;   // 152576 B
        hipFuncSetAttribute((const void*)k_persist,
                            hipFuncAttributeMaxDynamicSharedMemorySize, smem_bytes);
        const f16* XinF_c = XinF;
        const f16* pW0_c = pW0;
        const f16* pW1_c = pW1;
        f16 *h0_v = h0, *h1_v = h1;
        const float *b0_v = b0, *b1_v = b1;
        unsigned* flags_v = flags;
        void* kargs[] = {
            (void*)&XinF_c,
            (void*)&h0_v, (void*)&h1_v,
            (void*)&pW0_c, (void*)&pW1_c,
            (void*)&b0_v, (void*)&b1_v,
            (void*)&flags_v
        };
        hipLaunchCooperativeKernel((void*)k_persist, dim3(256), dim3(512),
                                   kargs, smem_bytes, stream);
    }

    // h1[511] lives at h1 + 512*HBUF
    k_out<<<BB, 128, 0, stream>>>(h1 + (size_t)512 * HBUF, Wo, bo, out);
}

// Round 6
// 3772.091 us; speedup vs baseline: 1.2367x; 1.1659x over previous
//
#include <hip/hip_runtime.h>
#include <math.h>

#define BB 64
#define TT 512
#define FF 512
#define DIN 1024
#define HH 1024
#define G4 4096
#define DOUT 128

typedef _Float16 f16;
typedef _Float16 f16x4 __attribute__((ext_vector_type(4)));
typedef _Float16 f16x8 __attribute__((ext_vector_type(8)));
typedef float f32x4 __attribute__((ext_vector_type(4)));

// A-fragment-linear layout for a [64 x 1024] fp16 activation matrix:
//   element (m, k) -> ((k>>5)*4 + (m>>4))*512 + ((((k>>3)&3)<<4) | (m&15))*8 + (k&7)
__device__ __forceinline__ size_t afrag_off(int m, int k) {
    return (size_t)(((k >> 5) * 4 + (m >> 4)) * 512 + (((((k >> 3) & 3) << 4) | (m & 15)) * 8) + (k & 7));
}

// agent-scope write-through 16-B store (IF authoritative for cross-XCD readers)
__device__ __forceinline__ void store_b128_sc1(void* p, f32x4 v) {
    asm volatile("global_store_dwordx4 %0, %1, off sc1" :: "v"(p), "v"(v) : "memory");
}

// ---------------------------------------------------------------------------
// Pack cat(W,U) [2048 x 4096] fp32 -> fp16 B-fragment-linear, z-cols reordered
// as col' = j*4 + g. Per (cg, kstep) a contiguous 1KB fragment tile.
// ---------------------------------------------------------------------------
__global__ __launch_bounds__(64) void k_pack(
    const float* __restrict__ W, const float* __restrict__ U, f16* __restrict__ out)
{
    const int kstep = blockIdx.x, cg = blockIdx.y, l = threadIdx.x;
    const int n = l & 15, q = l >> 4;
    const int stdcol = (n & 3) * HH + cg * 4 + (n >> 2);
    f16x8 v;
#pragma unroll
    for (int e = 0; e < 8; ++e) {
        int k = kstep * 32 + q * 8 + e;
        float s = (k < DIN) ? W[(size_t)k * G4 + stdcol] : U[(size_t)(k - DIN) * G4 + stdcol];
        v[e] = (f16)s;
    }
    *(f16x8*)(out + ((size_t)(cg * 64 + kstep) * 64 + l) * 8) = v;
}

// ---------------------------------------------------------------------------
// Pack Wi [512 x 1024] fp32 -> fp16 B-frag (no gate reorder). Tile (nt, kstep).
// ---------------------------------------------------------------------------
__global__ __launch_bounds__(64) void k_pack_wi(
    const float* __restrict__ Wi, f16* __restrict__ out)
{
    const int kstep = blockIdx.x;   // 0..15
    const int nt    = blockIdx.y;   // 0..63
    const int l = threadIdx.x;
    const int n = nt * 16 + (l & 15), q = l >> 4;
    f16x8 v;
#pragma unroll
    for (int e = 0; e < 8; ++e)
        v[e] = (f16)Wi[(size_t)(kstep * 32 + q * 8 + e) * DIN + n];
    *(f16x8*)(out + ((size_t)(nt * 16 + kstep) * 64 + l) * 8) = v;
}

// ---------------------------------------------------------------------------
// MFMA input dense: XinF[t] = tanh(x[:,t,:] @ Wi + bi), f16 A-frag layout.
// One block per t; stage x[:,t,:] as f16 in LDS [64][520]; 4 waves x 4 N-groups.
// ---------------------------------------------------------------------------
__global__ __launch_bounds__(256) void k_dense_in2(
    const float* __restrict__ x, const f16* __restrict__ pWi,
    const float* __restrict__ bi, f16* __restrict__ XinF)
{
    extern __shared__ f16 xs[];   // 64 x 520 = 66560 B
    const int t = blockIdx.x;
    const int tid = threadIdx.x;

#pragma unroll
    for (int it = 0; it < 32; ++it) {
        int idx = tid + it * 256;          // 0..8191 float4s
        int r = idx >> 7, c4 = idx & 127;
        float4 v = *(const float4*)(x + ((size_t)r * TT + t) * FF + c4 * 4);
        f16x4 hv = {(f16)v.x, (f16)v.y, (f16)v.z, (f16)v.w};
        *(f16x4*)(xs + (size_t)r * 520 + c4 * 4) = hv;
    }
    __syncthreads();

    const int w = tid >> 6, lane = tid & 63;
    const int col = lane & 15, rq = lane >> 4;
#pragma unroll 1
    for (int g = 0; g < 4; ++g) {
        f32x4 acc[4][4];
#pragma unroll
        for (int a = 0; a < 4; ++a)
#pragma unroll
            for (int b = 0; b < 4; ++b) acc[a][b] = (f32x4){0.f, 0.f, 0.f, 0.f};
#pragma unroll 2
        for (int ks2 = 0; ks2 < 16; ++ks2) {
            f16x8 bf[4];
#pragma unroll
            for (int nn = 0; nn < 4; ++nn)
                bf[nn] = *(const f16x8*)(pWi + ((size_t)((w * 16 + g * 4 + nn) * 16 + ks2) * 64 + lane) * 8);
#pragma unroll
            for (int mt = 0; mt < 4; ++mt) {
                f16x8 af = *(const f16x8*)(xs + (size_t)(mt * 16 + col) * 520 + ks2 * 32 + rq * 8);
#pragma unroll
                for (int nn = 0; nn < 4; ++nn)
                    acc[mt][nn] = __builtin_amdgcn_mfma_f32_16x16x32_f16(af, bf[nn], acc[mt][nn], 0, 0, 0);
            }
        }
#pragma unroll
        for (int nn = 0; nn < 4; ++nn) {
            const int j = (w * 16 + g * 4 + nn) * 16 + col;
            const float bb = bi[j];
#pragma unroll
            for (int mt = 0; mt < 4; ++mt)
#pragma unroll
                for (int r = 0; r < 4; ++r)
                    XinF[(size_t)t * (BB * DIN) + afrag_off(mt * 16 + rq * 4 + r, j)]
                        = (f16)tanhf(acc[mt][nn][r] + bb);
        }
    }
}

// ---------------------------------------------------------------------------
// Persistent kernel, 256 blocks x 512 threads (1 block/CU).
// lay = bid&1, cgb = bid>>1 (8 hidden units). Weights in LDS once.
// Sync (round 6): SAME gate code as round 3 (tid0 polls go0p / goO, then
// __syncthreads). Arrival changed: producer tid0 fetch_adds a per-phase
// counter word (64-B strided, writers-only line); whoever sees old==127
// publishes go = p+1 directly. No aggregator block, no detect-poll hop,
// no block has special duty.
// CODEGEN RULE (rounds 1/2/5 failures): the phase body must stay textually
// in the round-0 shape -- if(pre){load batch} gate if(!pre){load batch}
// mfma-loop -- at top level. Only the polled ADDRESS may change.
// h: write-once history, sc1 write-through 16-B stores. Cell state c in regs.
// Epilogue: conflict-free buf[4 kq][64 rows][stride 20] f32, repack folded
// into n==1 reduce (validated rounds 1-3).
// ---------------------------------------------------------------------------
__global__ __launch_bounds__(512, 2) void k_persist(
    const f16* __restrict__ XinF,
    f16* __restrict__ h0b_, f16* __restrict__ h1b_,
    const f16* __restrict__ pW0, const f16* __restrict__ pW1,
    const float* __restrict__ b0, const float* __restrict__ b1,
    unsigned* __restrict__ flags)
{
    extern __shared__ char smem[];
    f16*   bsh  = (f16*)smem;                    // 131072 B weight fragments
    float* buf  = (float*)(smem + 131072);       // 4 x 64 x 20 f32 = 20480 B
    f16*   hrow = (f16*)(smem + 131072 + 20480); // 64 x 8 f16 = 1024 B

    const int lay = blockIdx.x & 1;
    const int cgb = blockIdx.x >> 1;
    const int tid = threadIdx.x;
    const int wv = tid >> 6, lane = tid & 63;
    const int kq = wv >> 1, mh = wv & 1;

    // go words (same addresses as round 3): go0 at +2048, go1 at +2080
    unsigned* goO  = flags + 2048 + (lay ? 32 : 0);   // own-layer go (publish target)
    unsigned* go0p = flags + 2048;                    // L0 go (gate)
    // per-phase arrival counters, 16 words (64 B) apart, writers-only lines
    unsigned* cnt0 = flags + 4096;                    // L0: [513 * 16]
    unsigned* cnt1 = flags + 4096 + 513 * 16;         // L1: [513 * 16]
    unsigned* cntOwn = lay ? cnt1 : cnt0;

    // ---- stage this block's weight slice into LDS (once) ----
    {
        const f16x8* s8 = (const f16x8*)((lay ? pW1 : pW0) + (size_t)(cgb * 2) * 64 * 512);
        f16x8* d8 = (f16x8*)bsh;
#pragma unroll
        for (int it = 0; it < 16; ++it) d8[tid + it * 512] = s8[tid + it * 512];
    }

    // ---- epilogue-role constants ----
    const float* bias = lay ? b1 : b0;
    const int erow = tid & 63, ejl = (tid >> 6) & 3;
    float bz[2][4];
    float creg[2] = {0.f, 0.f};
    if (tid < 256) {
#pragma unroll
        for (int n = 0; n < 2; ++n) {
            const int jg = (cgb * 2 + n) * 4 + ejl;
#pragma unroll
            for (int g = 0; g < 4; ++g) bz[n][g] = bias[g * HH + jg];
        }
    }

    const size_t HBUF = (size_t)BB * DIN;
    const f16* bq = bsh + (size_t)(kq * 16 * 64 + lane) * 8;
    const int colw = lane & 15, rg = lane >> 4;
    __syncthreads();

    for (int p = 0; p <= TT; ++p) {
        if (lay == 0 && p == TT) break;          // L0 finished at p=511
        const bool active = lay ? (p >= 1) : true;

        if (active) {
            const f16* Abase;
            if (lay == 0) Abase = (kq < 2) ? (XinF + (size_t)p * HBUF) : (h0b_ + (size_t)p * HBUF);
            else          Abase = (kq < 2) ? (h0b_ + (size_t)p * HBUF) : (h1b_ + (size_t)(p - 1) * HBUF);
            f16* hw = lay ? (h1b_ + (size_t)p * HBUF) : (h0b_ + (size_t)(p + 1) * HBUF);
            const f16* Ap = Abase + (size_t)(((kq & 1) * 64 + mh * 2) * 512) + (size_t)lane * 8;

            f16x8 a0v[16], a1v[16];
            const bool pre = (lay == 0) && (kq < 2);   // Xin is static: safe pre-barrier
            if (pre) {
#pragma unroll
                for (int ii = 0; ii < 16; ++ii) {
                    a0v[ii] = *(const f16x8*)(Ap + (size_t)(ii * 4) * 512);
                    a1v[ii] = *(const f16x8*)(Ap + (size_t)(ii * 4 + 1) * 512);
                }
            }

            // ---- wait for phase inputs ----
            if (lay == 0) {
                if (p > 0) {
                    if (tid == 0)
                        while (__hip_atomic_load(go0p, __ATOMIC_RELAXED, __HIP_MEMORY_SCOPE_AGENT) < (unsigned)p)
                            __builtin_amdgcn_s_sleep(1);
                    __syncthreads();
                }
            } else {
                if (tid == 0) {
                    while (__hip_atomic_load(go0p, __ATOMIC_RELAXED, __HIP_MEMORY_SCOPE_AGENT) < (unsigned)p)
                        __builtin_amdgcn_s_sleep(1);
                    while (__hip_atomic_load(goO, __ATOMIC_RELAXED, __HIP_MEMORY_SCOPE_AGENT) < (unsigned)p)
                        __builtin_amdgcn_s_sleep(1);
                }
                __syncthreads();
            }

            if (!pre) {
#pragma unroll
                for (int ii = 0; ii < 16; ++ii) {
                    a0v[ii] = *(const f16x8*)(Ap + (size_t)(ii * 4) * 512);
                    a1v[ii] = *(const f16x8*)(Ap + (size_t)(ii * 4 + 1) * 512);
                }
            }

            f32x4 acc00 = {0.f,0.f,0.f,0.f}, acc01 = {0.f,0.f,0.f,0.f};
            f32x4 acc10 = {0.f,0.f,0.f,0.f}, acc11 = {0.f,0.f,0.f,0.f};
#pragma unroll
            for (int ii = 0; ii < 16; ++ii) {
                f16x8 bb0 = *(const f16x8*)(bq + (size_t)ii * 512);
                f16x8 bb1 = *(const f16x8*)(bq + 32768 + (size_t)ii * 512);
                acc00 = __builtin_amdgcn_mfma_f32_16x16x32_f16(a0v[ii], bb0, acc00, 0, 0, 0);
                acc01 = __builtin_amdgcn_mfma_f32_16x16x32_f16(a0v[ii], bb1, acc01, 0, 0, 0);
                acc10 = __builtin_amdgcn_mfma_f32_16x16x32_f16(a1v[ii], bb0, acc10, 0, 0, 0);
                acc11 = __builtin_amdgcn_mfma_f32_16x16x32_f16(a1v[ii], bb1, acc11, 0, 0, 0);
            }

            // ---- epilogue: two n-rounds over conflict-free buf[kq][row][20] ----
            f16 hvv[2];
#pragma unroll 1
            for (int n = 0; n < 2; ++n) {
                float* t0 = buf + (size_t)kq * 1280 + (size_t)(mh * 32 + rg * 4) * 20 + colw;
#pragma unroll
                for (int r = 0; r < 4; ++r) {
                    t0[r * 20]           = n ? acc01[r] : acc00[r];
                    t0[16 * 20 + r * 20] = n ? acc11[r] : acc10[r];
                }
                __syncthreads();
                if (tid < 256) {
                    f32x4 z = {0.f, 0.f, 0.f, 0.f};
#pragma unroll
                    for (int k2 = 0; k2 < 4; ++k2)
                        z += *(const f32x4*)(buf + (size_t)k2 * 1280 + (size_t)erow * 20 + ejl * 4);
                    const float z0 = z[0] + bz[n][0];
                    const float z1 = z[1] + bz[n][1];
                    const float z2 = z[2] + bz[n][2];
                    const float z3 = z[3] + bz[n][3];
                    const float ig = 1.f / (1.f + expf(-z0));
                    const float fg = 1.f / (1.f + expf(-z1));
                    const float cc = tanhf(z2);
                    const float og = 1.f / (1.f + expf(-z3));
                    const float cn = fg * creg[n] + ig * cc;
                    creg[n] = cn;
                    hvv[n] = (f16)(og * tanhf(cn));
                    if (n == 1) {   // fold repack into the last reduce round
                        hrow[erow * 8 + ejl]     = hvv[0];
                        hrow[erow * 8 + 4 + ejl] = hvv[1];
                    }
                }
                __syncthreads();
            }

            // ---- one 16-B sc1 store per row (wave0 only) ----
            if (tid < 64) {
                f32x4 v = *(f32x4*)(hrow + tid * 8);
                store_b128_sc1(hw + afrag_off(tid, cgb * 8), v);
            }
        }

        // ---- arrival: wave0 drains h stores; LAST arriver publishes go ----
        asm volatile("s_waitcnt vmcnt(0)" ::: "memory");
        if (tid == 0) {
            unsigned old = __hip_atomic_fetch_add(&cntOwn[(size_t)p * 16], 1u,
                                                  __ATOMIC_RELAXED, __HIP_MEMORY_SCOPE_AGENT);
            if (old == 127u)
                __hip_atomic_store(goO, (unsigned)(p + 1),
                                   __ATOMIC_RELAXED, __HIP_MEMORY_SCOPE_AGENT);
        }
    }
}

// ---------------------------------------------------------------------------
// Kernel 3: out[b][o] = tanh(h1[b,:] @ Wo[:,o] + bo[o]); h1 in fp16 A-frag.
// ---------------------------------------------------------------------------
__global__ __launch_bounds__(128) void k_out(
    const f16* __restrict__ h1f, const float* __restrict__ Wo,
    const float* __restrict__ bo, float* __restrict__ out)
{
    __shared__ float hs[HH];
    const int b = blockIdx.x;
    for (int i = threadIdx.x; i < HH; i += 128) hs[i] = (float)h1f[afrag_off(b, i)];
    __syncthreads();
    const int o = threadIdx.x;
    float acc = 0.f;
    for (int k = 0; k < HH; ++k) acc += hs[k] * Wo[k * DOUT + o];
    out[b * DOUT + o] = tanhf(acc + bo[o]);
}

// ---------------------------------------------------------------------------
extern "C" void kernel_launch(void* const* d_in, const int* in_sizes, int n_in,
                              void* d_out, int out_size, void* d_ws, size_t ws_size,
                              hipStream_t stream)
{
    const float* x  = (const float*)d_in[0];
    const float* Wi = (const float*)d_in[1];
    const float* bi = (const float*)d_in[2];
    const float* W0 = (const float*)d_in[3];
    const float* U0 = (const float*)d_in[4];
    const float* b0 = (const float*)d_in[5];
    const float* W1 = (const float*)d_in[6];
    const float* U1 = (const float*)d_in[7];
    const float* b1 = (const float*)d_in[8];
    const float* Wo = (const float*)d_in[9];
    const float* bo = (const float*)d_in[10];
    float* out = (float*)d_out;

    f16* ws16 = (f16*)d_ws;
    const size_t HBUF = (size_t)BB * DIN;          // 65536 f16
    f16* XinF = ws16;                              // 512 bufs
    f16* pW0  = XinF + (size_t)TT * HBUF;
    f16* pW1  = pW0 + (size_t)2048 * G4;
    f16* pWi  = pW1 + (size_t)2048 * G4;           // 512*1024
    f16* h0   = pWi + (size_t)FF * DIN;            // 513 bufs (write-once hist)
    f16* h1   = h0 + (size_t)513 * HBUF;           // 513 bufs
    unsigned* flags = (unsigned*)(h1 + (size_t)513 * HBUF);

    // zero initial h0[-1], h1[-1], go words, and counter region (~82 KB)
    hipMemsetAsync(h0, 0, HBUF * sizeof(f16), stream);
    hipMemsetAsync(h1, 0, HBUF * sizeof(f16), stream);
    hipMemsetAsync(flags, 0, 131072, stream);

    k_pack<<<dim3(64, 256), 64, 0, stream>>>(W0, U0, pW0);
    k_pack<<<dim3(64, 256), 64, 0, stream>>>(W1, U1, pW1);
    k_pack_wi<<<dim3(16, 64), 64, 0, stream>>>(Wi, pWi);

    hipFuncSetAttribute((const void*)k_dense_in2,
                        hipFuncAttributeMaxDynamicSharedMemorySize, 66560);
    k_dense_in2<<<TT, 256, 66560, stream>>>(x, pWi, bi, XinF);

    {
        const int smem_bytes = 131072 + 20480 + 1024;   // 152576 B
        hipFuncSetAttribute((const void*)k_persist,
                            hipFuncAttributeMaxDynamicSharedMemorySize, smem_bytes);
        const f16* XinF_c = XinF;
        const f16* pW0_c = pW0;
        const f16* pW1_c = pW1;
        f16 *h0_v = h0, *h1_v = h1;
        const float *b0_v = b0, *b1_v = b1;
        unsigned* flags_v = flags;
        void* kargs[] = {
            (void*)&XinF_c,
            (void*)&h0_v, (void*)&h1_v,
            (void*)&pW0_c, (void*)&pW1_c,
            (void*)&b0_v, (void*)&b1_v,
            (void*)&flags_v
        };
        hipLaunchCooperativeKernel((void*)k_persist, dim3(256), dim3(512),
                                   kargs, smem_bytes, stream);
    }

    // h1[511] lives at h1 + 512*HBUF
    k_out<<<BB, 128, 0, stream>>>(h1 + (size_t)512 * HBUF, Wo, bo, out);
}